// Round 11
// baseline (94.637 us; speedup 1.0000x reference)
//
#include <hip/hip_runtime.h>
#include <hip/hip_bf16.h>
#include <cstdint>
#include <cstddef>

#define SDIM 4096
#define CDIM 256
#define HSZ (64 * 4096)  // shorts per 64x4096 panel
#define POS ((size_t)2 * SDIM * CDIM)  // po panel stride (shorts) per t-split

typedef __attribute__((ext_vector_type(8))) short bf16x8;
typedef __attribute__((ext_vector_type(8))) __bf16 bfv8;
typedef __attribute__((ext_vector_type(4))) float f32x4;
typedef __attribute__((ext_vector_type(16))) float f32x16;

__device__ __forceinline__ float bf2f(short u) {
  union { uint32_t i; float f; } v; v.i = ((uint32_t)(uint16_t)u) << 16; return v.f;
}
__device__ __forceinline__ short bfc(float f) { return __builtin_bit_cast(short, (__bf16)f); }
__device__ __forceinline__ short4 pk4(float a, float b, float c, float d) {
  short4 r; r.x = bfc(a); r.y = bfc(b); r.z = bfc(c); r.w = bfc(d); return r;
}
// short2-pattern so the compiler can fuse to v_cvt_pk_bf16_f32 (m240: don't hand-asm)
__device__ __forceinline__ unsigned pkbf(float lo, float hi) {
  union { short s[2]; unsigned u; } r;
  r.s[0] = bfc(lo); r.s[1] = bfc(hi);
  return r.u;
}
__device__ __forceinline__ f32x4 MFMA(bf16x8 a, bf16x8 b, f32x4 c) {
  return __builtin_amdgcn_mfma_f32_16x16x32_bf16(
      __builtin_bit_cast(bfv8, a), __builtin_bit_cast(bfv8, b), c, 0, 0, 0);
}
__device__ __forceinline__ f32x16 MFMA32(bf16x8 a, bf16x8 b, f32x16 c) {
  return __builtin_amdgcn_mfma_f32_32x32x16_bf16(
      __builtin_bit_cast(bfv8, a), __builtin_bit_cast(bfv8, b), c, 0, 0, 0);
}

// log2(e) / sqrt(256): folded into Q at GEMM epilogue; softmax uses exp2 directly.
#define SCQ 0.09016844f

// ---------------- prep1: GN partial sums (blocks 0..511) + weight cvt (512..767) -----
__global__ __launch_bounds__(256) void prep1_k(
    const float* __restrict__ x, const float* __restrict__ wq,
    const float* __restrict__ wo, float* __restrict__ gnws,
    short* __restrict__ wqb, short* __restrict__ wob) {
  __shared__ float red[8];
  int blk = blockIdx.x;
  int tid = threadIdx.x;
  if (blk < 512) {
    // one (b,g) channel-chunk: bg = blk>>3, channel-in-group = blk&7 (4096 elems)
    const float4* xv = (const float4*)(x + (size_t)(blk >> 3) * 32768 + (blk & 7) * 4096);
    float sum = 0.f, sq = 0.f;
#pragma unroll
    for (int i = 0; i < 4; ++i) {
      float4 v = xv[tid + i * 256];
      sum += (v.x + v.y) + (v.z + v.w);
      sq += (v.x * v.x + v.y * v.y) + (v.z * v.z + v.w * v.w);
    }
#pragma unroll
    for (int m = 1; m < 64; m <<= 1) {
      sum += __shfl_xor(sum, m);
      sq += __shfl_xor(sq, m);
    }
    if ((tid & 63) == 0) { red[(tid >> 6) * 2] = sum; red[(tid >> 6) * 2 + 1] = sq; }
    __syncthreads();
    if (tid == 0) {
      gnws[blk * 2] = red[0] + red[2] + red[4] + red[6];
      gnws[blk * 2 + 1] = red[1] + red[3] + red[5] + red[7];
    }
  } else {
    int i = (blk - 512) * 256 + tid;  // float4 index
    if (i < 49152) {
      float4 v = ((const float4*)wq)[i];
      ((short4*)wqb)[i] = pk4(v.x, v.y, v.z, v.w);
    } else {
      float4 v = ((const float4*)wo)[i - 49152];
      ((short4*)wob)[i - 49152] = pk4(v.x, v.y, v.z, v.w);
    }
  }
}

// ---------------- GN apply -> normed^T[s][c] (bf16), 512 blocks ----------------------
__global__ __launch_bounds__(256) void gn_apply_k(
    const float* __restrict__ x, const float* __restrict__ gnws,
    const float* __restrict__ gamma, const float* __restrict__ beta,
    short* __restrict__ normedT) {
  int blk = blockIdx.x;
  int bg = blk >> 3, sc = blk & 7;
  int g = bg & 31, b = bg >> 5;
  int tid = threadIdx.x;
  float sum = 0.f, sq = 0.f;
#pragma unroll
  for (int c = 0; c < 8; ++c) {
    sum += gnws[(bg * 8 + c) * 2];
    sq += gnws[(bg * 8 + c) * 2 + 1];
  }
  float mean = sum * (1.f / 32768.f);
  float var = sq * (1.f / 32768.f) - mean * mean;
  float rstd = rsqrtf(var + 1e-5f);
  float ga[8], be[8];
#pragma unroll
  for (int c = 0; c < 8; ++c) {
    ga[c] = gamma[g * 8 + c] * rstd;
    be[c] = beta[g * 8 + c] - mean * ga[c];
  }
  const float* xg = x + (size_t)bg * 32768;
  short* nt = normedT + (size_t)b * SDIM * CDIM + g * 8;
#pragma unroll
  for (int it = 0; it < 2; ++it) {
    int s = sc * 512 + it * 256 + tid;
    float v[8];
#pragma unroll
    for (int c = 0; c < 8; ++c) v[c] = xg[c * 4096 + s] * ga[c] + be[c];
    union { short4 h[2]; bf16x8 v8; } o;
    o.h[0] = pk4(v[0], v[1], v[2], v[3]);
    o.h[1] = pk4(v[4], v[5], v[6], v[7]);
    *(bf16x8*)(nt + (size_t)s * CDIM) = o.v8;
  }
}

// ---------------- QKV GEMM: A=W rows (global), B=normed^T tile (LDS-staged) ----------
__global__ __launch_bounds__(256) void gemm_qkv(const short* __restrict__ W,
                                                const short* __restrict__ XT,
                                                short* __restrict__ qkv) {
  constexpr int XS = 264;  // pad: 132 words/row = +4 banks/row -> 2-way (free)
  __shared__ short xs[64 * XS];
  int bx = blockIdx.x;           // o-block 0..11
  int by = blockIdx.y;           // s-block 0..63
  int bz = blockIdx.z;           // b
  int tid = threadIdx.x;
  {
    int r = tid >> 2, c0 = (tid & 3) * 64;
    const short* src = XT + ((size_t)bz * SDIM + by * 64 + r) * CDIM + c0;
    short* dst = xs + r * XS + c0;
#pragma unroll
    for (int i = 0; i < 8; ++i)
      *(bf16x8*)(dst + i * 8) = *(const bf16x8*)(src + i * 8);
  }
  __syncthreads();
  int w = tid >> 6, lane = tid & 63;
  int sl = lane & 15, kg = lane >> 4;
  const short* Wr = W + (size_t)(bx * 64 + w * 16 + sl) * CDIM + kg * 8;
  f32x4 zero = {0.f, 0.f, 0.f, 0.f};
  f32x4 acc[4] = {zero, zero, zero, zero};
#pragma unroll
  for (int kk = 0; kk < 8; ++kk) {
    bf16x8 a = *(const bf16x8*)(Wr + kk * 32);
#pragma unroll
    for (int nb = 0; nb < 4; ++nb) {
      bf16x8 bfr = *(const bf16x8*)(xs + (nb * 16 + sl) * XS + kk * 32 + kg * 8);
      acc[nb] = MFMA(a, bfr, acc[nb]);
    }
  }
  int n = bx / 3, sub = bx % 3;
  size_t hbase = (size_t)(bz * 4 + n) * 3 * HSZ;
  if (sub == 0) {
    short* qt = qkv + hbase;
#pragma unroll
    for (int nb = 0; nb < 4; ++nb) {
      int s = by * 64 + nb * 16 + sl;
      *(short4*)(qt + (size_t)s * 64 + w * 16 + kg * 4) =
          pk4(acc[nb][0] * SCQ, acc[nb][1] * SCQ, acc[nb][2] * SCQ, acc[nb][3] * SCQ);
    }
  } else if (sub == 1) {
    short* kt = qkv + hbase + HSZ;
#pragma unroll
    for (int nb = 0; nb < 4; ++nb) {
      int s = by * 64 + nb * 16 + sl;
      *(short4*)(kt + (size_t)s * 64 + w * 16 + kg * 4) =
          pk4(acc[nb][0], acc[nb][1], acc[nb][2], acc[nb][3]);
    }
  } else {
    short* vp = qkv + hbase + 2 * HSZ;
#pragma unroll
    for (int nb = 0; nb < 4; ++nb) {
      int s = by * 64 + nb * 16 + sl;
#pragma unroll
      for (int r = 0; r < 4; ++r)
        vp[(size_t)(w * 16 + kg * 4 + r) * SDIM + s] = bfc(acc[nb][r]);
    }
  }
}

// ---------------- flash attention: 512 blocks (t-split x4), 512 thr ------------------
// Block = 8 waves x 32 s-cols = 256 s-cols, ALL sharing one K/V tile stream (36KB LDS,
// double-buffered, reg prefetch). Each block covers 1024 t (16 steps of 64).
// P in registers (pk + permlane32_swap). No online max (Q pre-scaled by log2e/16).
// l computed via MFMA with all-ones B (row-sums of P) — no VALU adds.
// waves_per_eu(4,4): force VGPR budget to 128 so accumulators stay in arch VGPRs
// (at the default the compiler squeezed to 64 VGPR -> AGPR shuffle tax on every step).
// Writes UNNORMALIZED partial O' (bf16) to po[tb][b][s][c] and l to pl[tb][nb][s].
#define ZERO16 {0.f,0.f,0.f,0.f,0.f,0.f,0.f,0.f,0.f,0.f,0.f,0.f,0.f,0.f,0.f,0.f}
#define TSTR 72           // LDS row stride (shorts): 144B -> +4 banks/row
#define TILE (64 * TSTR)  // 4608 shorts per 64x64 tile
#define BF1 ((short)0x3F80)  // bf16 1.0
__global__ __launch_bounds__(512)
__attribute__((amdgpu_waves_per_eu(4, 4)))
void attn_k(const short* __restrict__ qkv, short* __restrict__ po,
            float* __restrict__ pl) {
  __shared__ short smem[2 * 2 * TILE];  // [buf][K|V] = 36KB

  int blk = blockIdx.x;
  int nb = blk & 7;          // (b*4+n) — XCD-grouped for L2 locality
  int tb = (blk >> 3) & 3;   // t-quarter
  int sblk = blk >> 5;       // 0..15
  int tid = threadIdx.x;
  int w = tid >> 6, lane = tid & 63;
  int l5 = lane & 31, h = lane >> 5;

  size_t hbase = (size_t)nb * 3 * HSZ;
  const short* qt = qkv + hbase;
  const short* kt = qkv + hbase + HSZ;      // K^T [t][d]
  const short* vp = qkv + hbase + 2 * HSZ;  // V [d][t]

  int s0w = sblk * 256 + w * 32;

  // Q fragments (B operand): col s = l5, k = d = kc*16 + h*8 + j
  bf16x8 qf[4];
#pragma unroll
  for (int kc = 0; kc < 4; ++kc)
    qf[kc] = *(const bf16x8*)(qt + (size_t)(s0w + l5) * 64 + kc * 16 + h * 8);

  const bf16x8 ones = {BF1, BF1, BF1, BF1, BF1, BF1, BF1, BF1};

  // staging ids: 512 threads stage one K chunk + one V chunk each
  int srow = tid >> 3;   // row 0..63
  int sch = tid & 7;     // 8-short chunk
  int tbase = tb * 1024;

  // prefetch tile 0 into regs, stage
  bf16x8 kreg, vreg;
  kreg = *(const bf16x8*)(kt + (size_t)(tbase + srow) * 64 + sch * 8);
  vreg = *(const bf16x8*)(vp + (size_t)srow * SDIM + tbase + sch * 8);
  *(bf16x8*)(smem + srow * TSTR + sch * 8) = kreg;
  *(bf16x8*)(smem + TILE + srow * TSTR + sch * 8) = vreg;
  __syncthreads();

  f32x16 acc_o0 = ZERO16, acc_o1 = ZERO16, acc_l = ZERO16;

  for (int step = 0; step < 16; ++step) {
    short* kbuf = smem + (step & 1) * 2 * TILE;
    short* vbuf = kbuf + TILE;
    // prefetch next tile (global -> regs), hidden under compute
    if (step + 1 < 16) {
      int t1 = tbase + (step + 1) * 64;
      kreg = *(const bf16x8*)(kt + (size_t)(t1 + srow) * 64 + sch * 8);
      vreg = *(const bf16x8*)(vp + (size_t)srow * SDIM + t1 + sch * 8);
    }

    // QK^T: A = K^T rows (LDS), B = Q regs. D: col s=l5, row t=(r&3)+8*(r>>2)+4h
    f32x16 accs0 = ZERO16, accs1 = ZERO16;
    __builtin_amdgcn_s_setprio(1);
#pragma unroll
    for (int kc = 0; kc < 4; ++kc) {
      bf16x8 k0 = *(const bf16x8*)(kbuf + l5 * TSTR + (kc * 2 + h) * 8);
      bf16x8 k1 = *(const bf16x8*)(kbuf + (32 + l5) * TSTR + (kc * 2 + h) * 8);
      accs0 = MFMA32(k0, qf[kc], accs0);
      accs1 = MFMA32(k1, qf[kc], accs1);
    }
    __builtin_amdgcn_s_setprio(0);

    // softmax: P = exp2(score), no max subtraction
    float p0[16], p1[16];
#pragma unroll
    for (int r = 0; r < 16; ++r) p0[r] = __builtin_amdgcn_exp2f(accs0[r]);
#pragma unroll
    for (int r = 0; r < 16; ++r) p1[r] = __builtin_amdgcn_exp2f(accs1[r]);

    // P -> A-frag via pack + permlane32_swap; PV: B = V rows from LDS; l via B=ones
    __builtin_amdgcn_s_setprio(1);
#define PV_TC(pp, tcb, tc)                                                        \
    {                                                                             \
      unsigned a0 = pkbf(pp[8 * tcb + 0], pp[8 * tcb + 1]);                       \
      unsigned a1 = pkbf(pp[8 * tcb + 2], pp[8 * tcb + 3]);                       \
      unsigned b0 = pkbf(pp[8 * tcb + 4], pp[8 * tcb + 5]);                       \
      unsigned b1 = pkbf(pp[8 * tcb + 6], pp[8 * tcb + 7]);                       \
      asm volatile("v_permlane32_swap_b32 %0, %1" : "+v"(a0), "+v"(b0));          \
      asm volatile("v_permlane32_swap_b32 %0, %1" : "+v"(a1), "+v"(b1));          \
      union { unsigned u[4]; bf16x8 v; } F;                                       \
      F.u[0] = a0; F.u[1] = a1; F.u[2] = b0; F.u[3] = b1;                         \
      int c8 = (tc * 2 + h) * 8;                                                  \
      bf16x8 v0 = *(const bf16x8*)(vbuf + l5 * TSTR + c8);                        \
      bf16x8 v1 = *(const bf16x8*)(vbuf + (32 + l5) * TSTR + c8);                 \
      acc_o0 = MFMA32(F.v, v0, acc_o0);                                           \
      acc_o1 = MFMA32(F.v, v1, acc_o1);                                           \
      acc_l = MFMA32(F.v, ones, acc_l);                                           \
    }
    PV_TC(p0, 0, 0)
    PV_TC(p0, 1, 1)
    PV_TC(p1, 0, 2)
    PV_TC(p1, 1, 3)
#undef PV_TC
    __builtin_amdgcn_s_setprio(0);

    // stage next tile into the other buffer
    if (step + 1 < 16) {
      short* kn = smem + ((step + 1) & 1) * 2 * TILE;
      *(bf16x8*)(kn + srow * TSTR + sch * 8) = kreg;
      *(bf16x8*)(kn + TILE + srow * TSTR + sch * 8) = vreg;
    }
    __syncthreads();
  }

  // l[s] sits in acc_l rows (all cols equal); write from one col per h group
  if (l5 == 0) {
    float* plp = pl + ((size_t)tb * 8 + nb) * SDIM + s0w;
#pragma unroll
    for (int r = 0; r < 16; ++r) {
      int srw = (r & 3) + 8 * (r >> 2) + 4 * h;
      plp[srw] = acc_l[r];
    }
  }
  int n = nb & 3, b = nb >> 2;
#pragma unroll
  for (int r = 0; r < 16; ++r) {
    int srw = (r & 3) + 8 * (r >> 2) + 4 * h;
    int sg = s0w + srw;
    size_t rowb = ((size_t)(tb * 2 + b) * SDIM + sg) * CDIM + n * 64;
    po[rowb + l5] = bfc(acc_o0[r]);
    po[rowb + 32 + l5] = bfc(acc_o1[r]);
  }
}

// ---------------- final GEMM: merge-once in LDS, all 256 o per block -----------------
// Block (by: 32 s, bz: b), 512 thr. Stage A[32][256] = (Σ_tb po_tb)/Σl (bf16, LDS),
// then 8 waves: wave w computes o in [w*32, w*32+32) via A=W rows, B=A_lds rows.
// out[b][o][s] = D + bias[o] + x[b][o][s]
__global__ __launch_bounds__(512) void gemm_out(const short* __restrict__ po,
                                                const float* __restrict__ pl,
                                                const short* __restrict__ WO,
                                                const float* __restrict__ bias,
                                                const float* __restrict__ resid,
                                                float* __restrict__ out) {
  constexpr int AS = 264;
  __shared__ short als[32 * AS];
  int by = blockIdx.x;  // s-block of 32
  int bz = blockIdx.y;  // b
  int tid = threadIdx.x;
  {
    int row = tid >> 4;           // 32 rows, 16 threads each
    int c0 = (tid & 15) * 16;     // 16 shorts per thread
    int srow = by * 32 + row;
    int n = c0 >> 6;
    float l = 0.f;
#pragma unroll
    for (int t = 0; t < 4; ++t) l += pl[(size_t)(t * 8 + bz * 4 + n) * SDIM + srow];
    float inv = 1.f / l;
    const short* Ap = po + ((size_t)bz * SDIM + srow) * CDIM + c0;
    float f[16];
#pragma unroll
    for (int j = 0; j < 16; ++j) f[j] = 0.f;
#pragma unroll
    for (int t = 0; t < 4; ++t) {
      bf16x8 u0 = *(const bf16x8*)(Ap + t * POS);
      bf16x8 u1 = *(const bf16x8*)(Ap + t * POS + 8);
#pragma unroll
      for (int j = 0; j < 8; ++j) { f[j] += bf2f(u0[j]); f[8 + j] += bf2f(u1[j]); }
    }
    union { unsigned u[4]; bf16x8 v; } o0, o1;
#pragma unroll
    for (int j = 0; j < 4; ++j) {
      o0.u[j] = pkbf(f[2 * j] * inv, f[2 * j + 1] * inv);
      o1.u[j] = pkbf(f[8 + 2 * j] * inv, f[9 + 2 * j] * inv);
    }
    *(bf16x8*)(als + row * AS + c0) = o0.v;
    *(bf16x8*)(als + row * AS + c0 + 8) = o1.v;
  }
  __syncthreads();
  int w = tid >> 6, lane = tid & 63;
  int l5 = lane & 31, h = lane >> 5;
  const short* Wr = WO + (size_t)(w * 32 + l5) * CDIM + h * 8;
  f32x16 acc = ZERO16;
#pragma unroll
  for (int kk = 0; kk < 16; ++kk) {
    bf16x8 wf = *(const bf16x8*)(Wr + kk * 16);
    bf16x8 af = *(const bf16x8*)(als + l5 * AS + kk * 16 + h * 8);
    acc = MFMA32(wf, af, acc);  // D[o][s]: col = s = l5, row r -> o-local
  }
  int s = by * 32 + l5;
#pragma unroll
  for (int r = 0; r < 16; ++r) {
    int ol = (r & 3) + 8 * (r >> 2) + 4 * h;
    int o = w * 32 + ol;
    size_t idx = ((size_t)bz * CDIM + o) * SDIM + s;
    out[idx] = acc[r] + bias[o] + resid[idx];
  }
}

extern "C" void kernel_launch(void* const* d_in, const int* in_sizes, int n_in,
                              void* d_out, int out_size, void* d_ws, size_t ws_size,
                              hipStream_t stream) {
  const float* x = (const float*)d_in[0];
  const float* gamma = (const float*)d_in[1];
  const float* beta = (const float*)d_in[2];
  const float* wqkv = (const float*)d_in[3];
  const float* wout = (const float*)d_in[4];
  const float* bout = (const float*)d_in[5];
  float* out = (float*)d_out;

  // ws (shorts): wq_bf | wo_bf | qkv | po(4 panels; normedT overlaid on its start,
  // dead before attn writes po) | pl(f32) | gnws(f32)   ≈ 30.4 MB
  short* wq_bf = (short*)d_ws;
  short* wo_bf = wq_bf + 768 * 256;
  short* qkvb = wo_bf + 256 * 256;
  short* po = qkvb + (size_t)2 * 768 * SDIM;
  short* normedT = po;  // overlay: normedT (1 panel) ⊂ po region (4 panels)
  float* pl = (float*)(po + 4 * POS);
  float* gnws = pl + 4 * 8 * SDIM;

  hipLaunchKernelGGL(prep1_k, dim3(768), dim3(256), 0, stream, x, wqkv, wout, gnws,
                     wq_bf, wo_bf);
  hipLaunchKernelGGL(gn_apply_k, dim3(512), dim3(256), 0, stream, x, gnws, gamma, beta,
                     normedT);
  hipLaunchKernelGGL(gemm_qkv, dim3(12, 64, 2), dim3(256), 0, stream, wq_bf, normedT,
                     qkvb);
  hipLaunchKernelGGL(attn_k, dim3(512), dim3(512), 0, stream, qkvb, po, pl);
  hipLaunchKernelGGL(gemm_out, dim3(128, 2), dim3(512), 0, stream, po, pl, wo_bf,
                     bout, x, out);
}

// Round 12
// 78.077 us; speedup vs baseline: 1.2121x; 1.2121x over previous
//
#include <hip/hip_runtime.h>
#include <hip/hip_bf16.h>
#include <cstdint>
#include <cstddef>

#define SDIM 4096
#define CDIM 256
#define HSZ (64 * 4096)  // shorts per 64x4096 panel
#define POS ((size_t)2 * SDIM * CDIM)  // po panel stride (shorts) per t-split

typedef __attribute__((ext_vector_type(8))) short bf16x8;
typedef __attribute__((ext_vector_type(8))) __bf16 bfv8;
typedef __attribute__((ext_vector_type(4))) float f32x4;
typedef __attribute__((ext_vector_type(16))) float f32x16;

__device__ __forceinline__ float bf2f(short u) {
  union { uint32_t i; float f; } v; v.i = ((uint32_t)(uint16_t)u) << 16; return v.f;
}
__device__ __forceinline__ short bfc(float f) { return __builtin_bit_cast(short, (__bf16)f); }
__device__ __forceinline__ short4 pk4(float a, float b, float c, float d) {
  short4 r; r.x = bfc(a); r.y = bfc(b); r.z = bfc(c); r.w = bfc(d); return r;
}
// short2-pattern so the compiler can fuse to v_cvt_pk_bf16_f32 (m240: don't hand-asm)
__device__ __forceinline__ unsigned pkbf(float lo, float hi) {
  union { short s[2]; unsigned u; } r;
  r.s[0] = bfc(lo); r.s[1] = bfc(hi);
  return r.u;
}
__device__ __forceinline__ f32x4 MFMA(bf16x8 a, bf16x8 b, f32x4 c) {
  return __builtin_amdgcn_mfma_f32_16x16x32_bf16(
      __builtin_bit_cast(bfv8, a), __builtin_bit_cast(bfv8, b), c, 0, 0, 0);
}
__device__ __forceinline__ f32x16 MFMA32(bf16x8 a, bf16x8 b, f32x16 c) {
  return __builtin_amdgcn_mfma_f32_32x32x16_bf16(
      __builtin_bit_cast(bfv8, a), __builtin_bit_cast(bfv8, b), c, 0, 0, 0);
}

// log2(e) / sqrt(256): folded into Q at GEMM epilogue; softmax uses exp2 directly.
#define SCQ 0.09016844f

// ---------------- prep1: GN partial sums (blocks 0..511) + weight cvt (512..767) -----
__global__ __launch_bounds__(256) void prep1_k(
    const float* __restrict__ x, const float* __restrict__ wq,
    const float* __restrict__ wo, float* __restrict__ gnws,
    short* __restrict__ wqb, short* __restrict__ wob) {
  __shared__ float red[8];
  int blk = blockIdx.x;
  int tid = threadIdx.x;
  if (blk < 512) {
    // one (b,g) channel-chunk: bg = blk>>3, channel-in-group = blk&7 (4096 elems)
    const float4* xv = (const float4*)(x + (size_t)(blk >> 3) * 32768 + (blk & 7) * 4096);
    float sum = 0.f, sq = 0.f;
#pragma unroll
    for (int i = 0; i < 4; ++i) {
      float4 v = xv[tid + i * 256];
      sum += (v.x + v.y) + (v.z + v.w);
      sq += (v.x * v.x + v.y * v.y) + (v.z * v.z + v.w * v.w);
    }
#pragma unroll
    for (int m = 1; m < 64; m <<= 1) {
      sum += __shfl_xor(sum, m);
      sq += __shfl_xor(sq, m);
    }
    if ((tid & 63) == 0) { red[(tid >> 6) * 2] = sum; red[(tid >> 6) * 2 + 1] = sq; }
    __syncthreads();
    if (tid == 0) {
      gnws[blk * 2] = red[0] + red[2] + red[4] + red[6];
      gnws[blk * 2 + 1] = red[1] + red[3] + red[5] + red[7];
    }
  } else {
    int i = (blk - 512) * 256 + tid;  // float4 index
    if (i < 49152) {
      float4 v = ((const float4*)wq)[i];
      ((short4*)wqb)[i] = pk4(v.x, v.y, v.z, v.w);
    } else {
      float4 v = ((const float4*)wo)[i - 49152];
      ((short4*)wob)[i - 49152] = pk4(v.x, v.y, v.z, v.w);
    }
  }
}

// ---------------- GN apply -> normed^T[s][c] (bf16), 512 blocks ----------------------
__global__ __launch_bounds__(256) void gn_apply_k(
    const float* __restrict__ x, const float* __restrict__ gnws,
    const float* __restrict__ gamma, const float* __restrict__ beta,
    short* __restrict__ normedT) {
  int blk = blockIdx.x;
  int bg = blk >> 3, sc = blk & 7;
  int g = bg & 31, b = bg >> 5;
  int tid = threadIdx.x;
  float sum = 0.f, sq = 0.f;
#pragma unroll
  for (int c = 0; c < 8; ++c) {
    sum += gnws[(bg * 8 + c) * 2];
    sq += gnws[(bg * 8 + c) * 2 + 1];
  }
  float mean = sum * (1.f / 32768.f);
  float var = sq * (1.f / 32768.f) - mean * mean;
  float rstd = rsqrtf(var + 1e-5f);
  float ga[8], be[8];
#pragma unroll
  for (int c = 0; c < 8; ++c) {
    ga[c] = gamma[g * 8 + c] * rstd;
    be[c] = beta[g * 8 + c] - mean * ga[c];
  }
  const float* xg = x + (size_t)bg * 32768;
  short* nt = normedT + (size_t)b * SDIM * CDIM + g * 8;
#pragma unroll
  for (int it = 0; it < 2; ++it) {
    int s = sc * 512 + it * 256 + tid;
    float v[8];
#pragma unroll
    for (int c = 0; c < 8; ++c) v[c] = xg[c * 4096 + s] * ga[c] + be[c];
    union { short4 h[2]; bf16x8 v8; } o;
    o.h[0] = pk4(v[0], v[1], v[2], v[3]);
    o.h[1] = pk4(v[4], v[5], v[6], v[7]);
    *(bf16x8*)(nt + (size_t)s * CDIM) = o.v8;
  }
}

// ---------------- QKV GEMM: one head per block (Q,K,V panels share the X tile) -------
// Block (n: head, by: 64 s, bz: b), 256 thr. Stage X^T[64][256] once; wave w computes
// rows [w*16, w*16+16) of EACH of the Q/K/V 64-row panels — each LDS B-fragment feeds
// 3 MFMAs. Epilogue: Q^T (scaled), K^T, V as in the attention layout.
__global__ __launch_bounds__(256) void gemm_qkv(const short* __restrict__ W,
                                                const short* __restrict__ XT,
                                                short* __restrict__ qkv) {
  constexpr int XS = 264;  // pad: 132 words/row = +4 banks/row -> 2-way (free)
  __shared__ short xs[64 * XS];
  int n = blockIdx.x;            // head 0..3
  int by = blockIdx.y;           // s-block 0..63
  int bz = blockIdx.z;           // b
  int tid = threadIdx.x;
  {
    int r = tid >> 2, c0 = (tid & 3) * 64;
    const short* src = XT + ((size_t)bz * SDIM + by * 64 + r) * CDIM + c0;
    short* dst = xs + r * XS + c0;
#pragma unroll
    for (int i = 0; i < 8; ++i)
      *(bf16x8*)(dst + i * 8) = *(const bf16x8*)(src + i * 8);
  }
  __syncthreads();
  int w = tid >> 6, lane = tid & 63;
  int sl = lane & 15, kg = lane >> 4;
  const short* Wq = W + (size_t)(n * 192 + w * 16 + sl) * CDIM + kg * 8;
  const short* Wk = Wq + (size_t)64 * CDIM;
  const short* Wv = Wq + (size_t)128 * CDIM;
  f32x4 zero = {0.f, 0.f, 0.f, 0.f};
  f32x4 accq[4] = {zero, zero, zero, zero};
  f32x4 acck[4] = {zero, zero, zero, zero};
  f32x4 accv[4] = {zero, zero, zero, zero};
#pragma unroll
  for (int kk = 0; kk < 8; ++kk) {
    bf16x8 aq = *(const bf16x8*)(Wq + kk * 32);
    bf16x8 ak = *(const bf16x8*)(Wk + kk * 32);
    bf16x8 av = *(const bf16x8*)(Wv + kk * 32);
#pragma unroll
    for (int nb = 0; nb < 4; ++nb) {
      bf16x8 bfr = *(const bf16x8*)(xs + (nb * 16 + sl) * XS + kk * 32 + kg * 8);
      accq[nb] = MFMA(aq, bfr, accq[nb]);
      acck[nb] = MFMA(ak, bfr, acck[nb]);
      accv[nb] = MFMA(av, bfr, accv[nb]);
    }
  }
  size_t hbase = (size_t)(bz * 4 + n) * 3 * HSZ;
  short* qt = qkv + hbase;
  short* kt = qkv + hbase + HSZ;
  short* vp = qkv + hbase + 2 * HSZ;
#pragma unroll
  for (int nb = 0; nb < 4; ++nb) {
    int s = by * 64 + nb * 16 + sl;
    *(short4*)(qt + (size_t)s * 64 + w * 16 + kg * 4) =
        pk4(accq[nb][0] * SCQ, accq[nb][1] * SCQ, accq[nb][2] * SCQ, accq[nb][3] * SCQ);
    *(short4*)(kt + (size_t)s * 64 + w * 16 + kg * 4) =
        pk4(acck[nb][0], acck[nb][1], acck[nb][2], acck[nb][3]);
#pragma unroll
    for (int r = 0; r < 4; ++r)
      vp[(size_t)(w * 16 + kg * 4 + r) * SDIM + s] = bfc(accv[nb][r]);
  }
}

// ---------------- flash attention: 512 blocks (t-split x4), 512 thr ------------------
// Block = 8 waves x 32 s-cols = 256 s-cols, ALL sharing one K/V tile stream (36KB LDS,
// double-buffered, reg prefetch). Each block covers 1024 t (16 steps of 64).
// P in registers (pk + permlane32_swap). No online max (Q pre-scaled by log2e/16).
// l computed via MFMA with all-ones B (row-sums of P) — no VALU adds.
// Writes UNNORMALIZED partial O' (bf16) to po[tb][b][s][c] and l to pl[tb][nb][s].
#define ZERO16 {0.f,0.f,0.f,0.f,0.f,0.f,0.f,0.f,0.f,0.f,0.f,0.f,0.f,0.f,0.f,0.f}
#define TSTR 72           // LDS row stride (shorts): 144B -> +4 banks/row
#define TILE (64 * TSTR)  // 4608 shorts per 64x64 tile
#define BF1 ((short)0x3F80)  // bf16 1.0
__global__ __launch_bounds__(512, 4) void attn_k(const short* __restrict__ qkv,
                                                 short* __restrict__ po,
                                                 float* __restrict__ pl) {
  __shared__ short smem[2 * 2 * TILE];  // [buf][K|V] = 36KB

  int blk = blockIdx.x;
  int nb = blk & 7;          // (b*4+n) — XCD-grouped for L2 locality
  int tb = (blk >> 3) & 3;   // t-quarter
  int sblk = blk >> 5;       // 0..15
  int tid = threadIdx.x;
  int w = tid >> 6, lane = tid & 63;
  int l5 = lane & 31, h = lane >> 5;

  size_t hbase = (size_t)nb * 3 * HSZ;
  const short* qt = qkv + hbase;
  const short* kt = qkv + hbase + HSZ;      // K^T [t][d]
  const short* vp = qkv + hbase + 2 * HSZ;  // V [d][t]

  int s0w = sblk * 256 + w * 32;

  // Q fragments (B operand): col s = l5, k = d = kc*16 + h*8 + j
  bf16x8 qf[4];
#pragma unroll
  for (int kc = 0; kc < 4; ++kc)
    qf[kc] = *(const bf16x8*)(qt + (size_t)(s0w + l5) * 64 + kc * 16 + h * 8);

  const bf16x8 ones = {BF1, BF1, BF1, BF1, BF1, BF1, BF1, BF1};

  // staging ids: 512 threads stage one K chunk + one V chunk each
  int srow = tid >> 3;   // row 0..63
  int sch = tid & 7;     // 8-short chunk
  int tbase = tb * 1024;

  // prefetch tile 0 into regs, stage
  bf16x8 kreg, vreg;
  kreg = *(const bf16x8*)(kt + (size_t)(tbase + srow) * 64 + sch * 8);
  vreg = *(const bf16x8*)(vp + (size_t)srow * SDIM + tbase + sch * 8);
  *(bf16x8*)(smem + srow * TSTR + sch * 8) = kreg;
  *(bf16x8*)(smem + TILE + srow * TSTR + sch * 8) = vreg;
  __syncthreads();

  f32x16 acc_o0 = ZERO16, acc_o1 = ZERO16, acc_l = ZERO16;

  for (int step = 0; step < 16; ++step) {
    short* kbuf = smem + (step & 1) * 2 * TILE;
    short* vbuf = kbuf + TILE;
    // prefetch next tile (global -> regs), hidden under compute
    if (step + 1 < 16) {
      int t1 = tbase + (step + 1) * 64;
      kreg = *(const bf16x8*)(kt + (size_t)(t1 + srow) * 64 + sch * 8);
      vreg = *(const bf16x8*)(vp + (size_t)srow * SDIM + t1 + sch * 8);
    }

    // QK^T: A = K^T rows (LDS), B = Q regs. D: col s=l5, row t=(r&3)+8*(r>>2)+4h
    f32x16 accs0 = ZERO16, accs1 = ZERO16;
#pragma unroll
    for (int kc = 0; kc < 4; ++kc) {
      bf16x8 k0 = *(const bf16x8*)(kbuf + l5 * TSTR + (kc * 2 + h) * 8);
      bf16x8 k1 = *(const bf16x8*)(kbuf + (32 + l5) * TSTR + (kc * 2 + h) * 8);
      accs0 = MFMA32(k0, qf[kc], accs0);
      accs1 = MFMA32(k1, qf[kc], accs1);
    }

    // softmax: P = exp2(score), no max subtraction
    float p0[16], p1[16];
#pragma unroll
    for (int r = 0; r < 16; ++r) p0[r] = __builtin_amdgcn_exp2f(accs0[r]);
#pragma unroll
    for (int r = 0; r < 16; ++r) p1[r] = __builtin_amdgcn_exp2f(accs1[r]);

    // P -> A-frag via pack + permlane32_swap; PV: B = V rows from LDS; l via B=ones
#define PV_TC(pp, tcb, tc)                                                        \
    {                                                                             \
      unsigned a0 = pkbf(pp[8 * tcb + 0], pp[8 * tcb + 1]);                       \
      unsigned a1 = pkbf(pp[8 * tcb + 2], pp[8 * tcb + 3]);                       \
      unsigned b0 = pkbf(pp[8 * tcb + 4], pp[8 * tcb + 5]);                       \
      unsigned b1 = pkbf(pp[8 * tcb + 6], pp[8 * tcb + 7]);                       \
      asm volatile("v_permlane32_swap_b32 %0, %1" : "+v"(a0), "+v"(b0));          \
      asm volatile("v_permlane32_swap_b32 %0, %1" : "+v"(a1), "+v"(b1));          \
      union { unsigned u[4]; bf16x8 v; } F;                                       \
      F.u[0] = a0; F.u[1] = a1; F.u[2] = b0; F.u[3] = b1;                         \
      int c8 = (tc * 2 + h) * 8;                                                  \
      bf16x8 v0 = *(const bf16x8*)(vbuf + l5 * TSTR + c8);                        \
      bf16x8 v1 = *(const bf16x8*)(vbuf + (32 + l5) * TSTR + c8);                 \
      acc_o0 = MFMA32(F.v, v0, acc_o0);                                           \
      acc_o1 = MFMA32(F.v, v1, acc_o1);                                           \
      acc_l = MFMA32(F.v, ones, acc_l);                                           \
    }
    PV_TC(p0, 0, 0)
    PV_TC(p0, 1, 1)
    PV_TC(p1, 0, 2)
    PV_TC(p1, 1, 3)
#undef PV_TC

    // stage next tile into the other buffer
    if (step + 1 < 16) {
      short* kn = smem + ((step + 1) & 1) * 2 * TILE;
      *(bf16x8*)(kn + srow * TSTR + sch * 8) = kreg;
      *(bf16x8*)(kn + TILE + srow * TSTR + sch * 8) = vreg;
    }
    __syncthreads();
  }

  // l[s] sits in acc_l rows (all cols equal); write from one col per h group
  if (l5 == 0) {
    float* plp = pl + ((size_t)tb * 8 + nb) * SDIM + s0w;
#pragma unroll
    for (int r = 0; r < 16; ++r) {
      int srw = (r & 3) + 8 * (r >> 2) + 4 * h;
      plp[srw] = acc_l[r];
    }
  }
  int n = nb & 3, b = nb >> 2;
#pragma unroll
  for (int r = 0; r < 16; ++r) {
    int srw = (r & 3) + 8 * (r >> 2) + 4 * h;
    int sg = s0w + srw;
    size_t rowb = ((size_t)(tb * 2 + b) * SDIM + sg) * CDIM + n * 64;
    po[rowb + l5] = bfc(acc_o0[r]);
    po[rowb + 32 + l5] = bfc(acc_o1[r]);
  }
}

// ---------------- final GEMM: merge-once in LDS, all 256 o per block -----------------
// Block (by: 32 s, bz: b), 512 thr. Stage A[32][256] = (Σ_tb po_tb)/Σl (bf16, LDS),
// then 8 waves: wave w computes o in [w*32, w*32+32) via A=W rows, B=A_lds rows.
// out[b][o][s] = D + bias[o] + x[b][o][s]
__global__ __launch_bounds__(512) void gemm_out(const short* __restrict__ po,
                                                const float* __restrict__ pl,
                                                const short* __restrict__ WO,
                                                const float* __restrict__ bias,
                                                const float* __restrict__ resid,
                                                float* __restrict__ out) {
  constexpr int AS = 264;
  __shared__ short als[32 * AS];
  int by = blockIdx.x;  // s-block of 32
  int bz = blockIdx.y;  // b
  int tid = threadIdx.x;
  {
    int row = tid >> 4;           // 32 rows, 16 threads each
    int c0 = (tid & 15) * 16;     // 16 shorts per thread
    int srow = by * 32 + row;
    int n = c0 >> 6;
    float l = 0.f;
#pragma unroll
    for (int t = 0; t < 4; ++t) l += pl[(size_t)(t * 8 + bz * 4 + n) * SDIM + srow];
    float inv = 1.f / l;
    const short* Ap = po + ((size_t)bz * SDIM + srow) * CDIM + c0;
    float f[16];
#pragma unroll
    for (int j = 0; j < 16; ++j) f[j] = 0.f;
#pragma unroll
    for (int t = 0; t < 4; ++t) {
      bf16x8 u0 = *(const bf16x8*)(Ap + t * POS);
      bf16x8 u1 = *(const bf16x8*)(Ap + t * POS + 8);
#pragma unroll
      for (int j = 0; j < 8; ++j) { f[j] += bf2f(u0[j]); f[8 + j] += bf2f(u1[j]); }
    }
    union { unsigned u[4]; bf16x8 v; } o0, o1;
#pragma unroll
    for (int j = 0; j < 4; ++j) {
      o0.u[j] = pkbf(f[2 * j] * inv, f[2 * j + 1] * inv);
      o1.u[j] = pkbf(f[8 + 2 * j] * inv, f[9 + 2 * j] * inv);
    }
    *(bf16x8*)(als + row * AS + c0) = o0.v;
    *(bf16x8*)(als + row * AS + c0 + 8) = o1.v;
  }
  __syncthreads();
  int w = tid >> 6, lane = tid & 63;
  int l5 = lane & 31, h = lane >> 5;
  const short* Wr = WO + (size_t)(w * 32 + l5) * CDIM + h * 8;
  f32x16 acc = ZERO16;
#pragma unroll
  for (int kk = 0; kk < 16; ++kk) {
    bf16x8 wf = *(const bf16x8*)(Wr + kk * 16);
    bf16x8 af = *(const bf16x8*)(als + l5 * AS + kk * 16 + h * 8);
    acc = MFMA32(wf, af, acc);  // D[o][s]: col = s = l5, row r -> o-local
  }
  int s = by * 32 + l5;
#pragma unroll
  for (int r = 0; r < 16; ++r) {
    int ol = (r & 3) + 8 * (r >> 2) + 4 * h;
    int o = w * 32 + ol;
    size_t idx = ((size_t)bz * CDIM + o) * SDIM + s;
    out[idx] = acc[r] + bias[o] + resid[idx];
  }
}

extern "C" void kernel_launch(void* const* d_in, const int* in_sizes, int n_in,
                              void* d_out, int out_size, void* d_ws, size_t ws_size,
                              hipStream_t stream) {
  const float* x = (const float*)d_in[0];
  const float* gamma = (const float*)d_in[1];
  const float* beta = (const float*)d_in[2];
  const float* wqkv = (const float*)d_in[3];
  const float* wout = (const float*)d_in[4];
  const float* bout = (const float*)d_in[5];
  float* out = (float*)d_out;

  // ws (shorts): wq_bf | wo_bf | qkv | po(4 panels; normedT overlaid on its start,
  // dead before attn writes po) | pl(f32) | gnws(f32)   ≈ 30.4 MB
  short* wq_bf = (short*)d_ws;
  short* wo_bf = wq_bf + 768 * 256;
  short* qkvb = wo_bf + 256 * 256;
  short* po = qkvb + (size_t)2 * 768 * SDIM;
  short* normedT = po;  // overlay: normedT (1 panel) ⊂ po region (4 panels)
  float* pl = (float*)(po + 4 * POS);
  float* gnws = pl + 4 * 8 * SDIM;

  hipLaunchKernelGGL(prep1_k, dim3(768), dim3(256), 0, stream, x, wqkv, wout, gnws,
                     wq_bf, wo_bf);
  hipLaunchKernelGGL(gn_apply_k, dim3(512), dim3(256), 0, stream, x, gnws, gamma, beta,
                     normedT);
  hipLaunchKernelGGL(gemm_qkv, dim3(4, 64, 2), dim3(256), 0, stream, wq_bf, normedT,
                     qkvb);
  hipLaunchKernelGGL(attn_k, dim3(512), dim3(512), 0, stream, qkvb, po, pl);
  hipLaunchKernelGGL(gemm_out, dim3(128, 2), dim3(512), 0, stream, po, pl, wo_bf,
                     bout, x, out);
}

// Round 13
// 71.872 us; speedup vs baseline: 1.3168x; 1.0863x over previous
//
#include <hip/hip_runtime.h>
#include <hip/hip_bf16.h>
#include <cstdint>
#include <cstddef>

#define SDIM 4096
#define CDIM 256
#define HSZ (64 * 4096)  // shorts per 64x4096 panel
#define POS ((size_t)2 * SDIM * CDIM)  // po panel stride (shorts) per t-split

typedef __attribute__((ext_vector_type(8))) short bf16x8;
typedef __attribute__((ext_vector_type(8))) __bf16 bfv8;
typedef __attribute__((ext_vector_type(4))) float f32x4;
typedef __attribute__((ext_vector_type(16))) float f32x16;

__device__ __forceinline__ float bf2f(short u) {
  union { uint32_t i; float f; } v; v.i = ((uint32_t)(uint16_t)u) << 16; return v.f;
}
__device__ __forceinline__ short bfc(float f) { return __builtin_bit_cast(short, (__bf16)f); }
__device__ __forceinline__ short4 pk4(float a, float b, float c, float d) {
  short4 r; r.x = bfc(a); r.y = bfc(b); r.z = bfc(c); r.w = bfc(d); return r;
}
// short2-pattern so the compiler can fuse to v_cvt_pk_bf16_f32 (m240: don't hand-asm)
__device__ __forceinline__ unsigned pkbf(float lo, float hi) {
  union { short s[2]; unsigned u; } r;
  r.s[0] = bfc(lo); r.s[1] = bfc(hi);
  return r.u;
}
__device__ __forceinline__ f32x4 MFMA(bf16x8 a, bf16x8 b, f32x4 c) {
  return __builtin_amdgcn_mfma_f32_16x16x32_bf16(
      __builtin_bit_cast(bfv8, a), __builtin_bit_cast(bfv8, b), c, 0, 0, 0);
}
__device__ __forceinline__ f32x16 MFMA32(bf16x8 a, bf16x8 b, f32x16 c) {
  return __builtin_amdgcn_mfma_f32_32x32x16_bf16(
      __builtin_bit_cast(bfv8, a), __builtin_bit_cast(bfv8, b), c, 0, 0, 0);
}

// log2(e) / sqrt(256): folded into Q at GEMM epilogue; softmax uses exp2 directly.
#define SCQ 0.09016844f

// ---------------- prep1: GN partial sums (blocks 0..511) + weight cvt (512..767) -----
__global__ __launch_bounds__(256) void prep1_k(
    const float* __restrict__ x, const float* __restrict__ wq,
    const float* __restrict__ wo, float* __restrict__ gnws,
    short* __restrict__ wqb, short* __restrict__ wob) {
  __shared__ float red[8];
  int blk = blockIdx.x;
  int tid = threadIdx.x;
  if (blk < 512) {
    // one (b,g) channel-chunk: bg = blk>>3, channel-in-group = blk&7 (4096 elems)
    const float4* xv = (const float4*)(x + (size_t)(blk >> 3) * 32768 + (blk & 7) * 4096);
    float sum = 0.f, sq = 0.f;
#pragma unroll
    for (int i = 0; i < 4; ++i) {
      float4 v = xv[tid + i * 256];
      sum += (v.x + v.y) + (v.z + v.w);
      sq += (v.x * v.x + v.y * v.y) + (v.z * v.z + v.w * v.w);
    }
#pragma unroll
    for (int m = 1; m < 64; m <<= 1) {
      sum += __shfl_xor(sum, m);
      sq += __shfl_xor(sq, m);
    }
    if ((tid & 63) == 0) { red[(tid >> 6) * 2] = sum; red[(tid >> 6) * 2 + 1] = sq; }
    __syncthreads();
    if (tid == 0) {
      gnws[blk * 2] = red[0] + red[2] + red[4] + red[6];
      gnws[blk * 2 + 1] = red[1] + red[3] + red[5] + red[7];
    }
  } else {
    int i = (blk - 512) * 256 + tid;  // float4 index
    if (i < 49152) {
      float4 v = ((const float4*)wq)[i];
      ((short4*)wqb)[i] = pk4(v.x, v.y, v.z, v.w);
    } else {
      float4 v = ((const float4*)wo)[i - 49152];
      ((short4*)wob)[i - 49152] = pk4(v.x, v.y, v.z, v.w);
    }
  }
}

// ---------------- QKV GEMM with fused GroupNorm-apply --------------------------------
// Block (n: head, by: 64 s, bz: b), 256 thr.
// Phase 1: per-channel ga/be from gnws (+gamma/beta) into LDS.
// Phase 2: stage normed X^T[64][256] bf16 tile straight from fp32 x (coalesced rows).
// Phase 3: wave w computes rows [w*16,+16) of each Q/K/V panel — one LDS B-fragment
// feeds 3 MFMAs. Epilogue: Q^T (scaled by SCQ), K^T, V in the attention layout.
__global__ __launch_bounds__(256) void gemm_qkv(const short* __restrict__ W,
                                                const float* __restrict__ x,
                                                const float* __restrict__ gnws,
                                                const float* __restrict__ gamma,
                                                const float* __restrict__ beta,
                                                short* __restrict__ qkv) {
  constexpr int XS = 264;  // pad: 132 words/row = +4 banks/row
  __shared__ short xs[64 * XS];
  __shared__ float ga_s[256], be_s[256];
  int n = blockIdx.x;            // head 0..3
  int by = blockIdx.y;           // s-block 0..63
  int bz = blockIdx.z;           // b
  int tid = threadIdx.x;

  // phase 1: per-channel affine params
  {
    int c = tid;
    int g = c >> 3;
    const float* gw = gnws + (size_t)(bz * 32 + g) * 16;
    float sum = 0.f, sq = 0.f;
#pragma unroll
    for (int k = 0; k < 8; ++k) { sum += gw[k * 2]; sq += gw[k * 2 + 1]; }
    float mean = sum * (1.f / 32768.f);
    float var = sq * (1.f / 32768.f) - mean * mean;
    float rstd = rsqrtf(var + 1e-5f);
    float ga = gamma[c] * rstd;
    ga_s[c] = ga;
    be_s[c] = beta[c] - mean * ga;
  }
  __syncthreads();

  // phase 2: stage normed tile (transposed) from fp32 x
  {
    int s_loc = tid & 63;
    const float* xb = x + (size_t)bz * 256 * SDIM + by * 64 + s_loc;
#pragma unroll
    for (int it = 0; it < 8; ++it) {
      int c0 = ((tid >> 6) + it * 4) * 8;
      float v[8];
#pragma unroll
      for (int j = 0; j < 8; ++j)
        v[j] = xb[(size_t)(c0 + j) * SDIM] * ga_s[c0 + j] + be_s[c0 + j];
      union { short4 h[2]; bf16x8 v8; } o;
      o.h[0] = pk4(v[0], v[1], v[2], v[3]);
      o.h[1] = pk4(v[4], v[5], v[6], v[7]);
      *(bf16x8*)(xs + s_loc * XS + c0) = o.v8;
    }
  }
  __syncthreads();

  // phase 3: MFMA
  int w = tid >> 6, lane = tid & 63;
  int sl = lane & 15, kg = lane >> 4;
  const short* Wq = W + (size_t)(n * 192 + w * 16 + sl) * CDIM + kg * 8;
  const short* Wk = Wq + (size_t)64 * CDIM;
  const short* Wv = Wq + (size_t)128 * CDIM;
  f32x4 zero = {0.f, 0.f, 0.f, 0.f};
  f32x4 accq[4] = {zero, zero, zero, zero};
  f32x4 acck[4] = {zero, zero, zero, zero};
  f32x4 accv[4] = {zero, zero, zero, zero};
#pragma unroll
  for (int kk = 0; kk < 8; ++kk) {
    bf16x8 aq = *(const bf16x8*)(Wq + kk * 32);
    bf16x8 ak = *(const bf16x8*)(Wk + kk * 32);
    bf16x8 av = *(const bf16x8*)(Wv + kk * 32);
#pragma unroll
    for (int nb = 0; nb < 4; ++nb) {
      bf16x8 bfr = *(const bf16x8*)(xs + (nb * 16 + sl) * XS + kk * 32 + kg * 8);
      accq[nb] = MFMA(aq, bfr, accq[nb]);
      acck[nb] = MFMA(ak, bfr, acck[nb]);
      accv[nb] = MFMA(av, bfr, accv[nb]);
    }
  }
  size_t hbase = (size_t)(bz * 4 + n) * 3 * HSZ;
  short* qt = qkv + hbase;
  short* kt = qkv + hbase + HSZ;
  short* vp = qkv + hbase + 2 * HSZ;
#pragma unroll
  for (int nb = 0; nb < 4; ++nb) {
    int s = by * 64 + nb * 16 + sl;
    *(short4*)(qt + (size_t)s * 64 + w * 16 + kg * 4) =
        pk4(accq[nb][0] * SCQ, accq[nb][1] * SCQ, accq[nb][2] * SCQ, accq[nb][3] * SCQ);
    *(short4*)(kt + (size_t)s * 64 + w * 16 + kg * 4) =
        pk4(acck[nb][0], acck[nb][1], acck[nb][2], acck[nb][3]);
#pragma unroll
    for (int r = 0; r < 4; ++r)
      vp[(size_t)(w * 16 + kg * 4 + r) * SDIM + s] = bfc(accv[nb][r]);
  }
}

// ---------------- flash attention: 512 blocks (t-split x4), 512 thr ------------------
// Block = 8 waves x 32 s-cols = 256 s-cols, ALL sharing one K/V tile stream (36KB LDS,
// double-buffered, reg prefetch). Each block covers 1024 t (16 steps of 64).
// P in registers (pk + permlane32_swap). No online max (Q pre-scaled by log2e/16).
// l computed via MFMA with all-ones B (row-sums of P) — no VALU adds.
// Writes UNNORMALIZED partial O' (bf16) to po[tb][b][s][c] and l to pl[tb][nb][s].
#define ZERO16 {0.f,0.f,0.f,0.f,0.f,0.f,0.f,0.f,0.f,0.f,0.f,0.f,0.f,0.f,0.f,0.f}
#define TSTR 72           // LDS row stride (shorts): 144B -> +4 banks/row
#define TILE (64 * TSTR)  // 4608 shorts per 64x64 tile
#define BF1 ((short)0x3F80)  // bf16 1.0
__global__ __launch_bounds__(512, 4) void attn_k(const short* __restrict__ qkv,
                                                 short* __restrict__ po,
                                                 float* __restrict__ pl) {
  __shared__ short smem[2 * 2 * TILE];  // [buf][K|V] = 36KB

  int blk = blockIdx.x;
  int nb = blk & 7;          // (b*4+n) — XCD-grouped for L2 locality
  int tb = (blk >> 3) & 3;   // t-quarter
  int sblk = blk >> 5;       // 0..15
  int tid = threadIdx.x;
  int w = tid >> 6, lane = tid & 63;
  int l5 = lane & 31, h = lane >> 5;

  size_t hbase = (size_t)nb * 3 * HSZ;
  const short* qt = qkv + hbase;
  const short* kt = qkv + hbase + HSZ;      // K^T [t][d]
  const short* vp = qkv + hbase + 2 * HSZ;  // V [d][t]

  int s0w = sblk * 256 + w * 32;

  // Q fragments (B operand): col s = l5, k = d = kc*16 + h*8 + j
  bf16x8 qf[4];
#pragma unroll
  for (int kc = 0; kc < 4; ++kc)
    qf[kc] = *(const bf16x8*)(qt + (size_t)(s0w + l5) * 64 + kc * 16 + h * 8);

  const bf16x8 ones = {BF1, BF1, BF1, BF1, BF1, BF1, BF1, BF1};

  // staging ids: 512 threads stage one K chunk + one V chunk each
  int srow = tid >> 3;   // row 0..63
  int sch = tid & 7;     // 8-short chunk
  int tbase = tb * 1024;

  // prefetch tile 0 into regs, stage
  bf16x8 kreg, vreg;
  kreg = *(const bf16x8*)(kt + (size_t)(tbase + srow) * 64 + sch * 8);
  vreg = *(const bf16x8*)(vp + (size_t)srow * SDIM + tbase + sch * 8);
  *(bf16x8*)(smem + srow * TSTR + sch * 8) = kreg;
  *(bf16x8*)(smem + TILE + srow * TSTR + sch * 8) = vreg;
  __syncthreads();

  f32x16 acc_o0 = ZERO16, acc_o1 = ZERO16, acc_l = ZERO16;

  for (int step = 0; step < 16; ++step) {
    short* kbuf = smem + (step & 1) * 2 * TILE;
    short* vbuf = kbuf + TILE;
    // prefetch next tile (global -> regs), hidden under compute
    if (step + 1 < 16) {
      int t1 = tbase + (step + 1) * 64;
      kreg = *(const bf16x8*)(kt + (size_t)(t1 + srow) * 64 + sch * 8);
      vreg = *(const bf16x8*)(vp + (size_t)srow * SDIM + t1 + sch * 8);
    }

    // QK^T: A = K^T rows (LDS), B = Q regs. D: col s=l5, row t=(r&3)+8*(r>>2)+4h
    f32x16 accs0 = ZERO16, accs1 = ZERO16;
#pragma unroll
    for (int kc = 0; kc < 4; ++kc) {
      bf16x8 k0 = *(const bf16x8*)(kbuf + l5 * TSTR + (kc * 2 + h) * 8);
      bf16x8 k1 = *(const bf16x8*)(kbuf + (32 + l5) * TSTR + (kc * 2 + h) * 8);
      accs0 = MFMA32(k0, qf[kc], accs0);
      accs1 = MFMA32(k1, qf[kc], accs1);
    }

    // softmax: P = exp2(score), no max subtraction
    float p0[16], p1[16];
#pragma unroll
    for (int r = 0; r < 16; ++r) p0[r] = __builtin_amdgcn_exp2f(accs0[r]);
#pragma unroll
    for (int r = 0; r < 16; ++r) p1[r] = __builtin_amdgcn_exp2f(accs1[r]);

    // P -> A-frag via pack + permlane32_swap; PV: B = V rows from LDS; l via B=ones
#define PV_TC(pp, tcb, tc)                                                        \
    {                                                                             \
      unsigned a0 = pkbf(pp[8 * tcb + 0], pp[8 * tcb + 1]);                       \
      unsigned a1 = pkbf(pp[8 * tcb + 2], pp[8 * tcb + 3]);                       \
      unsigned b0 = pkbf(pp[8 * tcb + 4], pp[8 * tcb + 5]);                       \
      unsigned b1 = pkbf(pp[8 * tcb + 6], pp[8 * tcb + 7]);                       \
      asm volatile("v_permlane32_swap_b32 %0, %1" : "+v"(a0), "+v"(b0));          \
      asm volatile("v_permlane32_swap_b32 %0, %1" : "+v"(a1), "+v"(b1));          \
      union { unsigned u[4]; bf16x8 v; } F;                                       \
      F.u[0] = a0; F.u[1] = a1; F.u[2] = b0; F.u[3] = b1;                         \
      int c8 = (tc * 2 + h) * 8;                                                  \
      bf16x8 v0 = *(const bf16x8*)(vbuf + l5 * TSTR + c8);                        \
      bf16x8 v1 = *(const bf16x8*)(vbuf + (32 + l5) * TSTR + c8);                 \
      acc_o0 = MFMA32(F.v, v0, acc_o0);                                           \
      acc_o1 = MFMA32(F.v, v1, acc_o1);                                           \
      acc_l = MFMA32(F.v, ones, acc_l);                                           \
    }
    PV_TC(p0, 0, 0)
    PV_TC(p0, 1, 1)
    PV_TC(p1, 0, 2)
    PV_TC(p1, 1, 3)
#undef PV_TC

    // stage next tile into the other buffer
    if (step + 1 < 16) {
      short* kn = smem + ((step + 1) & 1) * 2 * TILE;
      *(bf16x8*)(kn + srow * TSTR + sch * 8) = kreg;
      *(bf16x8*)(kn + TILE + srow * TSTR + sch * 8) = vreg;
    }
    __syncthreads();
  }

  // l[s] sits in acc_l rows (all cols equal); write from one col per h group
  if (l5 == 0) {
    float* plp = pl + ((size_t)tb * 8 + nb) * SDIM + s0w;
#pragma unroll
    for (int r = 0; r < 16; ++r) {
      int srw = (r & 3) + 8 * (r >> 2) + 4 * h;
      plp[srw] = acc_l[r];
    }
  }
  int n = nb & 3, b = nb >> 2;
#pragma unroll
  for (int r = 0; r < 16; ++r) {
    int srw = (r & 3) + 8 * (r >> 2) + 4 * h;
    int sg = s0w + srw;
    size_t rowb = ((size_t)(tb * 2 + b) * SDIM + sg) * CDIM + n * 64;
    po[rowb + l5] = bfc(acc_o0[r]);
    po[rowb + 32 + l5] = bfc(acc_o1[r]);
  }
}

// ---------------- final GEMM: merge-once in LDS, all 256 o per block -----------------
// Block (by: 32 s, bz: b), 512 thr. Stage A[32][256] = (Σ_tb po_tb)/Σl (bf16, LDS),
// then 8 waves: wave w computes o in [w*32, w*32+32) via A=W rows, B=A_lds rows.
// out[b][o][s] = D + bias[o] + x[b][o][s]
__global__ __launch_bounds__(512) void gemm_out(const short* __restrict__ po,
                                                const float* __restrict__ pl,
                                                const short* __restrict__ WO,
                                                const float* __restrict__ bias,
                                                const float* __restrict__ resid,
                                                float* __restrict__ out) {
  constexpr int AS = 264;
  __shared__ short als[32 * AS];
  int by = blockIdx.x;  // s-block of 32
  int bz = blockIdx.y;  // b
  int tid = threadIdx.x;
  {
    int row = tid >> 4;           // 32 rows, 16 threads each
    int c0 = (tid & 15) * 16;     // 16 shorts per thread
    int srow = by * 32 + row;
    int n = c0 >> 6;
    float l = 0.f;
#pragma unroll
    for (int t = 0; t < 4; ++t) l += pl[(size_t)(t * 8 + bz * 4 + n) * SDIM + srow];
    float inv = 1.f / l;
    const short* Ap = po + ((size_t)bz * SDIM + srow) * CDIM + c0;
    float f[16];
#pragma unroll
    for (int j = 0; j < 16; ++j) f[j] = 0.f;
#pragma unroll
    for (int t = 0; t < 4; ++t) {
      bf16x8 u0 = *(const bf16x8*)(Ap + t * POS);
      bf16x8 u1 = *(const bf16x8*)(Ap + t * POS + 8);
#pragma unroll
      for (int j = 0; j < 8; ++j) { f[j] += bf2f(u0[j]); f[8 + j] += bf2f(u1[j]); }
    }
    union { unsigned u[4]; bf16x8 v; } o0, o1;
#pragma unroll
    for (int j = 0; j < 4; ++j) {
      o0.u[j] = pkbf(f[2 * j] * inv, f[2 * j + 1] * inv);
      o1.u[j] = pkbf(f[8 + 2 * j] * inv, f[9 + 2 * j] * inv);
    }
    *(bf16x8*)(als + row * AS + c0) = o0.v;
    *(bf16x8*)(als + row * AS + c0 + 8) = o1.v;
  }
  __syncthreads();
  int w = tid >> 6, lane = tid & 63;
  int l5 = lane & 31, h = lane >> 5;
  const short* Wr = WO + (size_t)(w * 32 + l5) * CDIM + h * 8;
  f32x16 acc = ZERO16;
#pragma unroll
  for (int kk = 0; kk < 16; ++kk) {
    bf16x8 wf = *(const bf16x8*)(Wr + kk * 16);
    bf16x8 af = *(const bf16x8*)(als + l5 * AS + kk * 16 + h * 8);
    acc = MFMA32(wf, af, acc);  // D[o][s]: col = s = l5, row r -> o-local
  }
  int s = by * 32 + l5;
#pragma unroll
  for (int r = 0; r < 16; ++r) {
    int ol = (r & 3) + 8 * (r >> 2) + 4 * h;
    int o = w * 32 + ol;
    size_t idx = ((size_t)bz * CDIM + o) * SDIM + s;
    out[idx] = acc[r] + bias[o] + resid[idx];
  }
}

extern "C" void kernel_launch(void* const* d_in, const int* in_sizes, int n_in,
                              void* d_out, int out_size, void* d_ws, size_t ws_size,
                              hipStream_t stream) {
  const float* x = (const float*)d_in[0];
  const float* gamma = (const float*)d_in[1];
  const float* beta = (const float*)d_in[2];
  const float* wqkv = (const float*)d_in[3];
  const float* wout = (const float*)d_in[4];
  const float* bout = (const float*)d_in[5];
  float* out = (float*)d_out;

  // ws (shorts): wq_bf | wo_bf | qkv | po(4 panels) | pl(f32) | gnws(f32)  ≈ 30 MB
  short* wq_bf = (short*)d_ws;
  short* wo_bf = wq_bf + 768 * 256;
  short* qkvb = wo_bf + 256 * 256;
  short* po = qkvb + (size_t)2 * 768 * SDIM;
  float* pl = (float*)(po + 4 * POS);
  float* gnws = pl + 4 * 8 * SDIM;

  hipLaunchKernelGGL(prep1_k, dim3(768), dim3(256), 0, stream, x, wqkv, wout, gnws,
                     wq_bf, wo_bf);
  hipLaunchKernelGGL(gemm_qkv, dim3(4, 64, 2), dim3(256), 0, stream, wq_bf, x, gnws,
                     gamma, beta, qkvb);
  hipLaunchKernelGGL(attn_k, dim3(512), dim3(512), 0, stream, qkvb, po, pl);
  hipLaunchKernelGGL(gemm_out, dim3(128, 2), dim3(512), 0, stream, po, pl, wo_bf,
                     bout, x, out);
}

// Round 14
// 69.811 us; speedup vs baseline: 1.3556x; 1.0295x over previous
//
#include <hip/hip_runtime.h>
#include <hip/hip_bf16.h>
#include <cstdint>
#include <cstddef>

#define SDIM 4096
#define CDIM 256
#define HSZ (64 * 4096)  // shorts per 64x4096 panel
#define POS ((size_t)2 * SDIM * CDIM)  // po panel stride (shorts) per t-split

typedef __attribute__((ext_vector_type(8))) short bf16x8;
typedef __attribute__((ext_vector_type(8))) __bf16 bfv8;
typedef __attribute__((ext_vector_type(4))) float f32x4;
typedef __attribute__((ext_vector_type(16))) float f32x16;

__device__ __forceinline__ float bf2f(short u) {
  union { uint32_t i; float f; } v; v.i = ((uint32_t)(uint16_t)u) << 16; return v.f;
}
__device__ __forceinline__ short bfc(float f) { return __builtin_bit_cast(short, (__bf16)f); }
__device__ __forceinline__ short4 pk4(float a, float b, float c, float d) {
  short4 r; r.x = bfc(a); r.y = bfc(b); r.z = bfc(c); r.w = bfc(d); return r;
}
// short2-pattern so the compiler can fuse to v_cvt_pk_bf16_f32 (m240: don't hand-asm)
__device__ __forceinline__ unsigned pkbf(float lo, float hi) {
  union { short s[2]; unsigned u; } r;
  r.s[0] = bfc(lo); r.s[1] = bfc(hi);
  return r.u;
}
__device__ __forceinline__ f32x4 MFMA(bf16x8 a, bf16x8 b, f32x4 c) {
  return __builtin_amdgcn_mfma_f32_16x16x32_bf16(
      __builtin_bit_cast(bfv8, a), __builtin_bit_cast(bfv8, b), c, 0, 0, 0);
}
__device__ __forceinline__ f32x16 MFMA32(bf16x8 a, bf16x8 b, f32x16 c) {
  return __builtin_amdgcn_mfma_f32_32x32x16_bf16(
      __builtin_bit_cast(bfv8, a), __builtin_bit_cast(bfv8, b), c, 0, 0, 0);
}

// log2(e) / sqrt(256): folded into Q at GEMM epilogue; softmax uses exp2 directly.
#define SCQ 0.09016844f

// ---------------- prep1: GN partial sums (blocks 0..511) + weight cvt (512..767) -----
__global__ __launch_bounds__(256) void prep1_k(
    const float* __restrict__ x, const float* __restrict__ wq,
    const float* __restrict__ wo, float* __restrict__ gnws,
    short* __restrict__ wqb, short* __restrict__ wob) {
  __shared__ float red[8];
  int blk = blockIdx.x;
  int tid = threadIdx.x;
  if (blk < 512) {
    // one (b,g) channel-chunk: bg = blk>>3, channel-in-group = blk&7 (4096 elems)
    const float4* xv = (const float4*)(x + (size_t)(blk >> 3) * 32768 + (blk & 7) * 4096);
    float sum = 0.f, sq = 0.f;
#pragma unroll
    for (int i = 0; i < 4; ++i) {
      float4 v = xv[tid + i * 256];
      sum += (v.x + v.y) + (v.z + v.w);
      sq += (v.x * v.x + v.y * v.y) + (v.z * v.z + v.w * v.w);
    }
#pragma unroll
    for (int m = 1; m < 64; m <<= 1) {
      sum += __shfl_xor(sum, m);
      sq += __shfl_xor(sq, m);
    }
    if ((tid & 63) == 0) { red[(tid >> 6) * 2] = sum; red[(tid >> 6) * 2 + 1] = sq; }
    __syncthreads();
    if (tid == 0) {
      gnws[blk * 2] = red[0] + red[2] + red[4] + red[6];
      gnws[blk * 2 + 1] = red[1] + red[3] + red[5] + red[7];
    }
  } else {
    int i = (blk - 512) * 256 + tid;  // float4 index
    if (i < 49152) {
      float4 v = ((const float4*)wq)[i];
      ((short4*)wqb)[i] = pk4(v.x, v.y, v.z, v.w);
    } else {
      float4 v = ((const float4*)wo)[i - 49152];
      ((short4*)wob)[i - 49152] = pk4(v.x, v.y, v.z, v.w);
    }
  }
}

// ---------------- QKV GEMM with fused GroupNorm-apply --------------------------------
// Flat grid 512, XCD-aware decode: blk = (tile%8) + 8*(n + 4*(tile/8)) so the 4 head-
// blocks of one (by,bz) tile share blk%8 -> same XCD -> x tile fetched from HBM once,
// L2-served for the other 3 heads.
// Phase 1: per-channel ga/be from gnws (+gamma/beta) into LDS.
// Phase 2: stage normed X^T[64][256] bf16 tile straight from fp32 x (coalesced rows).
// Phase 3: wave w computes rows [w*16,+16) of each Q/K/V panel — one LDS B-fragment
// feeds 3 MFMAs. Epilogue: Q^T (scaled by SCQ), K^T, V in the attention layout.
__global__ __launch_bounds__(256) void gemm_qkv(const short* __restrict__ W,
                                                const float* __restrict__ x,
                                                const float* __restrict__ gnws,
                                                const float* __restrict__ gamma,
                                                const float* __restrict__ beta,
                                                short* __restrict__ qkv) {
  constexpr int XS = 264;  // pad: 132 words/row = +4 banks/row
  __shared__ short xs[64 * XS];
  __shared__ float ga_s[256], be_s[256];
  int blk = blockIdx.x;
  int xcd = blk & 7;
  int rem = blk >> 3;
  int n = rem & 3;               // head 0..3
  int tile = (rem >> 2) * 8 + xcd;  // 0..127
  int by = tile & 63;            // s-block 0..63
  int bz = tile >> 6;            // b
  int tid = threadIdx.x;

  // phase 1: per-channel affine params
  {
    int c = tid;
    int g = c >> 3;
    const float* gw = gnws + (size_t)(bz * 32 + g) * 16;
    float sum = 0.f, sq = 0.f;
#pragma unroll
    for (int k = 0; k < 8; ++k) { sum += gw[k * 2]; sq += gw[k * 2 + 1]; }
    float mean = sum * (1.f / 32768.f);
    float var = sq * (1.f / 32768.f) - mean * mean;
    float rstd = rsqrtf(var + 1e-5f);
    float ga = gamma[c] * rstd;
    ga_s[c] = ga;
    be_s[c] = beta[c] - mean * ga;
  }
  __syncthreads();

  // phase 2: stage normed tile (transposed) from fp32 x
  {
    int s_loc = tid & 63;
    const float* xb = x + (size_t)bz * 256 * SDIM + by * 64 + s_loc;
#pragma unroll
    for (int it = 0; it < 8; ++it) {
      int c0 = ((tid >> 6) + it * 4) * 8;
      float v[8];
#pragma unroll
      for (int j = 0; j < 8; ++j)
        v[j] = xb[(size_t)(c0 + j) * SDIM] * ga_s[c0 + j] + be_s[c0 + j];
      union { short4 h[2]; bf16x8 v8; } o;
      o.h[0] = pk4(v[0], v[1], v[2], v[3]);
      o.h[1] = pk4(v[4], v[5], v[6], v[7]);
      *(bf16x8*)(xs + s_loc * XS + c0) = o.v8;
    }
  }
  __syncthreads();

  // phase 3: MFMA
  int w = tid >> 6, lane = tid & 63;
  int sl = lane & 15, kg = lane >> 4;
  const short* Wq = W + (size_t)(n * 192 + w * 16 + sl) * CDIM + kg * 8;
  const short* Wk = Wq + (size_t)64 * CDIM;
  const short* Wv = Wq + (size_t)128 * CDIM;
  f32x4 zero = {0.f, 0.f, 0.f, 0.f};
  f32x4 accq[4] = {zero, zero, zero, zero};
  f32x4 acck[4] = {zero, zero, zero, zero};
  f32x4 accv[4] = {zero, zero, zero, zero};
#pragma unroll
  for (int kk = 0; kk < 8; ++kk) {
    bf16x8 aq = *(const bf16x8*)(Wq + kk * 32);
    bf16x8 ak = *(const bf16x8*)(Wk + kk * 32);
    bf16x8 av = *(const bf16x8*)(Wv + kk * 32);
#pragma unroll
    for (int nb = 0; nb < 4; ++nb) {
      bf16x8 bfr = *(const bf16x8*)(xs + (nb * 16 + sl) * XS + kk * 32 + kg * 8);
      accq[nb] = MFMA(aq, bfr, accq[nb]);
      acck[nb] = MFMA(ak, bfr, acck[nb]);
      accv[nb] = MFMA(av, bfr, accv[nb]);
    }
  }
  size_t hbase = (size_t)(bz * 4 + n) * 3 * HSZ;
  short* qt = qkv + hbase;
  short* kt = qkv + hbase + HSZ;
  short* vp = qkv + hbase + 2 * HSZ;
#pragma unroll
  for (int nb = 0; nb < 4; ++nb) {
    int s = by * 64 + nb * 16 + sl;
    *(short4*)(qt + (size_t)s * 64 + w * 16 + kg * 4) =
        pk4(accq[nb][0] * SCQ, accq[nb][1] * SCQ, accq[nb][2] * SCQ, accq[nb][3] * SCQ);
    *(short4*)(kt + (size_t)s * 64 + w * 16 + kg * 4) =
        pk4(acck[nb][0], acck[nb][1], acck[nb][2], acck[nb][3]);
#pragma unroll
    for (int r = 0; r < 4; ++r)
      vp[(size_t)(w * 16 + kg * 4 + r) * SDIM + s] = bfc(accv[nb][r]);
  }
}

// ---------------- flash attention: 512 blocks (t-split x4), 512 thr ------------------
// Block = 8 waves x 32 s-cols = 256 s-cols, ALL sharing one K/V tile stream (36KB LDS,
// double-buffered, reg prefetch). Each block covers 1024 t (16 steps of 64).
// P in registers (pk + permlane32_swap). No online max (Q pre-scaled by log2e/16).
// l computed via MFMA with all-ones B (row-sums of P) — no VALU adds.
// Writes UNNORMALIZED partial O' (bf16) to po[tb][b][s][c] and l to pl[tb][nb][s].
#define ZERO16 {0.f,0.f,0.f,0.f,0.f,0.f,0.f,0.f,0.f,0.f,0.f,0.f,0.f,0.f,0.f,0.f}
#define TSTR 72           // LDS row stride (shorts): 144B -> +4 banks/row
#define TILE (64 * TSTR)  // 4608 shorts per 64x64 tile
#define BF1 ((short)0x3F80)  // bf16 1.0
__global__ __launch_bounds__(512, 4) void attn_k(const short* __restrict__ qkv,
                                                 short* __restrict__ po,
                                                 float* __restrict__ pl) {
  __shared__ short smem[2 * 2 * TILE];  // [buf][K|V] = 36KB

  int blk = blockIdx.x;
  int nb = blk & 7;          // (b*4+n) — XCD-grouped for L2 locality
  int tb = (blk >> 3) & 3;   // t-quarter
  int sblk = blk >> 5;       // 0..15
  int tid = threadIdx.x;
  int w = tid >> 6, lane = tid & 63;
  int l5 = lane & 31, h = lane >> 5;

  size_t hbase = (size_t)nb * 3 * HSZ;
  const short* qt = qkv + hbase;
  const short* kt = qkv + hbase + HSZ;      // K^T [t][d]
  const short* vp = qkv + hbase + 2 * HSZ;  // V [d][t]

  int s0w = sblk * 256 + w * 32;

  // Q fragments (B operand): col s = l5, k = d = kc*16 + h*8 + j
  bf16x8 qf[4];
#pragma unroll
  for (int kc = 0; kc < 4; ++kc)
    qf[kc] = *(const bf16x8*)(qt + (size_t)(s0w + l5) * 64 + kc * 16 + h * 8);

  const bf16x8 ones = {BF1, BF1, BF1, BF1, BF1, BF1, BF1, BF1};

  // staging ids: 512 threads stage one K chunk + one V chunk each
  int srow = tid >> 3;   // row 0..63
  int sch = tid & 7;     // 8-short chunk
  int tbase = tb * 1024;

  // prefetch tile 0 into regs, stage
  bf16x8 kreg, vreg;
  kreg = *(const bf16x8*)(kt + (size_t)(tbase + srow) * 64 + sch * 8);
  vreg = *(const bf16x8*)(vp + (size_t)srow * SDIM + tbase + sch * 8);
  *(bf16x8*)(smem + srow * TSTR + sch * 8) = kreg;
  *(bf16x8*)(smem + TILE + srow * TSTR + sch * 8) = vreg;
  __syncthreads();

  f32x16 acc_o0 = ZERO16, acc_o1 = ZERO16, acc_l = ZERO16;

  for (int step = 0; step < 16; ++step) {
    short* kbuf = smem + (step & 1) * 2 * TILE;
    short* vbuf = kbuf + TILE;
    // prefetch next tile (global -> regs), hidden under compute
    if (step + 1 < 16) {
      int t1 = tbase + (step + 1) * 64;
      kreg = *(const bf16x8*)(kt + (size_t)(t1 + srow) * 64 + sch * 8);
      vreg = *(const bf16x8*)(vp + (size_t)srow * SDIM + t1 + sch * 8);
    }

    // QK^T: A = K^T rows (LDS), B = Q regs. D: col s=l5, row t=(r&3)+8*(r>>2)+4h
    f32x16 accs0 = ZERO16, accs1 = ZERO16;
#pragma unroll
    for (int kc = 0; kc < 4; ++kc) {
      bf16x8 k0 = *(const bf16x8*)(kbuf + l5 * TSTR + (kc * 2 + h) * 8);
      bf16x8 k1 = *(const bf16x8*)(kbuf + (32 + l5) * TSTR + (kc * 2 + h) * 8);
      accs0 = MFMA32(k0, qf[kc], accs0);
      accs1 = MFMA32(k1, qf[kc], accs1);
    }

    // softmax: P = exp2(score), no max subtraction
    float p0[16], p1[16];
#pragma unroll
    for (int r = 0; r < 16; ++r) p0[r] = __builtin_amdgcn_exp2f(accs0[r]);
#pragma unroll
    for (int r = 0; r < 16; ++r) p1[r] = __builtin_amdgcn_exp2f(accs1[r]);

    // P -> A-frag via pack + permlane32_swap; PV: B = V rows from LDS; l via B=ones
#define PV_TC(pp, tcb, tc)                                                        \
    {                                                                             \
      unsigned a0 = pkbf(pp[8 * tcb + 0], pp[8 * tcb + 1]);                       \
      unsigned a1 = pkbf(pp[8 * tcb + 2], pp[8 * tcb + 3]);                       \
      unsigned b0 = pkbf(pp[8 * tcb + 4], pp[8 * tcb + 5]);                       \
      unsigned b1 = pkbf(pp[8 * tcb + 6], pp[8 * tcb + 7]);                       \
      asm volatile("v_permlane32_swap_b32 %0, %1" : "+v"(a0), "+v"(b0));          \
      asm volatile("v_permlane32_swap_b32 %0, %1" : "+v"(a1), "+v"(b1));          \
      union { unsigned u[4]; bf16x8 v; } F;                                       \
      F.u[0] = a0; F.u[1] = a1; F.u[2] = b0; F.u[3] = b1;                         \
      int c8 = (tc * 2 + h) * 8;                                                  \
      bf16x8 v0 = *(const bf16x8*)(vbuf + l5 * TSTR + c8);                        \
      bf16x8 v1 = *(const bf16x8*)(vbuf + (32 + l5) * TSTR + c8);                 \
      acc_o0 = MFMA32(F.v, v0, acc_o0);                                           \
      acc_o1 = MFMA32(F.v, v1, acc_o1);                                           \
      acc_l = MFMA32(F.v, ones, acc_l);                                           \
    }
    PV_TC(p0, 0, 0)
    PV_TC(p0, 1, 1)
    PV_TC(p1, 0, 2)
    PV_TC(p1, 1, 3)
#undef PV_TC

    // stage next tile into the other buffer
    if (step + 1 < 16) {
      short* kn = smem + ((step + 1) & 1) * 2 * TILE;
      *(bf16x8*)(kn + srow * TSTR + sch * 8) = kreg;
      *(bf16x8*)(kn + TILE + srow * TSTR + sch * 8) = vreg;
    }
    __syncthreads();
  }

  // l[s] sits in acc_l rows (all cols equal); write from one col per h group
  if (l5 == 0) {
    float* plp = pl + ((size_t)tb * 8 + nb) * SDIM + s0w;
#pragma unroll
    for (int r = 0; r < 16; ++r) {
      int srw = (r & 3) + 8 * (r >> 2) + 4 * h;
      plp[srw] = acc_l[r];
    }
  }
  int n = nb & 3, b = nb >> 2;
#pragma unroll
  for (int r = 0; r < 16; ++r) {
    int srw = (r & 3) + 8 * (r >> 2) + 4 * h;
    int sg = s0w + srw;
    size_t rowb = ((size_t)(tb * 2 + b) * SDIM + sg) * CDIM + n * 64;
    po[rowb + l5] = bfc(acc_o0[r]);
    po[rowb + 32 + l5] = bfc(acc_o1[r]);
  }
}

// ---------------- final GEMM: merge-once in LDS, all 256 o per block -----------------
// Block (by: 32 s, bz: b), 512 thr. Stage A[32][256] = (Σ_tb po_tb)/Σl (bf16, LDS),
// then 8 waves: wave w computes o in [w*32, w*32+32) via A=W rows, B=A_lds rows.
// out[b][o][s] = D + bias[o] + x[b][o][s]
__global__ __launch_bounds__(512) void gemm_out(const short* __restrict__ po,
                                                const float* __restrict__ pl,
                                                const short* __restrict__ WO,
                                                const float* __restrict__ bias,
                                                const float* __restrict__ resid,
                                                float* __restrict__ out) {
  constexpr int AS = 264;
  __shared__ short als[32 * AS];
  int by = blockIdx.x;  // s-block of 32
  int bz = blockIdx.y;  // b
  int tid = threadIdx.x;
  {
    int row = tid >> 4;           // 32 rows, 16 threads each
    int c0 = (tid & 15) * 16;     // 16 shorts per thread
    int srow = by * 32 + row;
    int n = c0 >> 6;
    float l = 0.f;
#pragma unroll
    for (int t = 0; t < 4; ++t) l += pl[(size_t)(t * 8 + bz * 4 + n) * SDIM + srow];
    float inv = 1.f / l;
    const short* Ap = po + ((size_t)bz * SDIM + srow) * CDIM + c0;
    float f[16];
#pragma unroll
    for (int j = 0; j < 16; ++j) f[j] = 0.f;
#pragma unroll
    for (int t = 0; t < 4; ++t) {
      bf16x8 u0 = *(const bf16x8*)(Ap + t * POS);
      bf16x8 u1 = *(const bf16x8*)(Ap + t * POS + 8);
#pragma unroll
      for (int j = 0; j < 8; ++j) { f[j] += bf2f(u0[j]); f[8 + j] += bf2f(u1[j]); }
    }
    union { unsigned u[4]; bf16x8 v; } o0, o1;
#pragma unroll
    for (int j = 0; j < 4; ++j) {
      o0.u[j] = pkbf(f[2 * j] * inv, f[2 * j + 1] * inv);
      o1.u[j] = pkbf(f[8 + 2 * j] * inv, f[9 + 2 * j] * inv);
    }
    *(bf16x8*)(als + row * AS + c0) = o0.v;
    *(bf16x8*)(als + row * AS + c0 + 8) = o1.v;
  }
  __syncthreads();
  int w = tid >> 6, lane = tid & 63;
  int l5 = lane & 31, h = lane >> 5;
  const short* Wr = WO + (size_t)(w * 32 + l5) * CDIM + h * 8;
  f32x16 acc = ZERO16;
#pragma unroll
  for (int kk = 0; kk < 16; ++kk) {
    bf16x8 wf = *(const bf16x8*)(Wr + kk * 16);
    bf16x8 af = *(const bf16x8*)(als + l5 * AS + kk * 16 + h * 8);
    acc = MFMA32(wf, af, acc);  // D[o][s]: col = s = l5, row r -> o-local
  }
  int s = by * 32 + l5;
#pragma unroll
  for (int r = 0; r < 16; ++r) {
    int ol = (r & 3) + 8 * (r >> 2) + 4 * h;
    int o = w * 32 + ol;
    size_t idx = ((size_t)bz * CDIM + o) * SDIM + s;
    out[idx] = acc[r] + bias[o] + resid[idx];
  }
}

extern "C" void kernel_launch(void* const* d_in, const int* in_sizes, int n_in,
                              void* d_out, int out_size, void* d_ws, size_t ws_size,
                              hipStream_t stream) {
  const float* x = (const float*)d_in[0];
  const float* gamma = (const float*)d_in[1];
  const float* beta = (const float*)d_in[2];
  const float* wqkv = (const float*)d_in[3];
  const float* wout = (const float*)d_in[4];
  const float* bout = (const float*)d_in[5];
  float* out = (float*)d_out;

  // ws (shorts): wq_bf | wo_bf | qkv | po(4 panels) | pl(f32) | gnws(f32)  ≈ 30 MB
  short* wq_bf = (short*)d_ws;
  short* wo_bf = wq_bf + 768 * 256;
  short* qkvb = wo_bf + 256 * 256;
  short* po = qkvb + (size_t)2 * 768 * SDIM;
  float* pl = (float*)(po + 4 * POS);
  float* gnws = pl + 4 * 8 * SDIM;

  hipLaunchKernelGGL(prep1_k, dim3(768), dim3(256), 0, stream, x, wqkv, wout, gnws,
                     wq_bf, wo_bf);
  hipLaunchKernelGGL(gemm_qkv, dim3(512), dim3(256), 0, stream, wq_bf, x, gnws,
                     gamma, beta, qkvb);
  hipLaunchKernelGGL(attn_k, dim3(512), dim3(512), 0, stream, qkvb, po, pl);
  hipLaunchKernelGGL(gemm_out, dim3(128, 2), dim3(512), 0, stream, po, pl, wo_bf,
                     bout, x, out);
}